// Round 8
// baseline (1766.086 us; speedup 1.0000x reference)
//
#include <hip/hip_runtime.h>

#define EMBED   300
#define HIDDEN  256
#define SEQ     256
#define NG      1024          // 4*HIDDEN
#define NL1     16
#define NL2     16
#define NBLK    96            // 16 L1 + 16 L2 + 64 helpers
#define CAP     (1 << 15)     // poll failsafe cap

typedef __attribute__((ext_vector_type(8))) short  short8;   // 8 bf16
typedef __attribute__((ext_vector_type(4))) float  f32x4;
typedef unsigned long long ull;

__device__ inline unsigned short f2bf(float f) {
    unsigned u = __builtin_bit_cast(unsigned, f);
    return (unsigned short)((u + 0x7FFFu + ((u >> 16) & 1u)) >> 16);   // RNE
}
__device__ inline float bf2f(unsigned short h) {
    unsigned u = (unsigned)h << 16;
    return __builtin_bit_cast(float, u);
}
__device__ inline float sigm(float x)  { return 1.0f / (1.0f + __expf(-x)); }
__device__ inline float tanh_(float x) { return 2.0f / (1.0f + __expf(-2.0f * x)) - 1.0f; }
__device__ inline int swzb(int c, int base) { return base ^ (((c >> 1) & 3) << 4); }

// relaxed agent-scope (LLC-coherent, per-XCD-L2 bypass) — proven r3/r5/r7
__device__ inline unsigned ld32a(const unsigned* p) {
    return __hip_atomic_load(p, __ATOMIC_RELAXED, __HIP_MEMORY_SCOPE_AGENT);
}
__device__ inline void st32a(unsigned* p, unsigned v) {
    __hip_atomic_store(p, v, __ATOMIC_RELAXED, __HIP_MEMORY_SCOPE_AGENT);
}
__device__ inline ull ld64a(const ull* p) {
    return __hip_atomic_load(p, __ATOMIC_RELAXED, __HIP_MEMORY_SCOPE_AGENT);
}
__device__ inline void st64a(ull* p, ull v) {
    __hip_atomic_store(p, v, __ATOMIC_RELAXED, __HIP_MEMORY_SCOPE_AGENT);
}
__device__ inline float ldf32a(const float* p) {
    return __builtin_bit_cast(float, ld32a((const unsigned*)p));
}
__device__ inline void stf32a(float* p, float v) {
    st32a((unsigned*)p, __builtin_bit_cast(unsigned, v));
}
__device__ inline short8 ldh16a(const unsigned short* p) {
    ull t0 = ld64a((const ull*)p);
    ull t1 = ld64a((const ull*)p + 1);
    union { ull q[2]; short8 s; } u;
    u.q[0] = t0; u.q[1] = t1;
    return u.s;
}

#define MFMA(a, b, c) __builtin_amdgcn_mfma_f32_16x16x32_bf16((a), (b), (c), 0, 0, 0)

// PACKED flag layout (u32 index): consecutive flags share a 64B line so a
// wave's poll lanes coalesce into one LLC transaction per line.
//   f1[i]  = flags[i]        (i<16, one line)   : e+2 after L1 i published h1[e]
//   f2[i]  = flags[16+i]     (i<16, one line)   : t+2 after L2 i finished step t
//   fh[p][s] = flags[32+p*32+s] (four lines)    : t+1 after helper stored gx1[t]
#define F1IX(i)    (i)
#define F2IX(i)    (16 + (i))
#define FHIX(p, s) (32 + (p) * 32 + (s))

__global__ __launch_bounds__(256, 1) void lstm_v8(
    const int*   __restrict__ xin,
    const float* __restrict__ emb,
    const float* __restrict__ W0, const float* __restrict__ b0,
    const float* __restrict__ W1, const float* __restrict__ b1,
    unsigned*       __restrict__ flags,
    unsigned short* __restrict__ h1,      // [4][64][256] bf16 ring
    unsigned short* __restrict__ h2,      // [2][64][256] bf16 ring
    float*          __restrict__ ring1,   // [4][64][1024] f32 (b0 folded)
    float*          __restrict__ out)     // [64][256] f32
{
    extern __shared__ char lds[];
    int* aliveP = (int*)(lds + 40960);
    const int tid = threadIdx.x, bid = blockIdx.x;
    const int w = tid >> 6, lane = tid & 63, l15 = lane & 15, q = lane >> 4;
    const int bbase = w * 16, arow = bbase + l15;
    bool alive = true;

    // wide poll: w==0 lanes each watch ONE u32 in a packed line
    auto wpoll = [&](const unsigned* p0, unsigned t0, float diag) -> bool {
        if (w == 0) {
            int n = 0;
            for (;;) {
                bool ok = (p0 == nullptr) || (ld32a(p0) >= t0);
                if (__all(ok)) break;
                if (++n > CAP) { if (lane == 0) stf32a(out, diag); alive = false; break; }
            }
        }
        if (tid == 0) *aliveP = alive ? 1 : 0;
        __syncthreads();
        return *aliveP != 0;
    };
    auto drain_sync = [&]() {
        asm volatile("s_waitcnt vmcnt(0)" ::: "memory");
        __syncthreads();
    };

    // =====================================================================
    if (bid < NL1) {                       // ---- L1 recurrence (16-unit stripes) ----
        const int u0 = bid * 16;
        { int r = tid >> 2, p = tid & 3;   // zero h1[-1] (slot 3), own stripe
          st64a((ull*)(h1 + 3 * 16384 + r * 256 + u0) + p, 0ULL); }
        short8 bfragR[8][4];
        #pragma unroll
        for (int s = 0; s < 8; ++s)
            #pragma unroll
            for (int nt = 0; nt < 4; ++nt)
                #pragma unroll
                for (int e2 = 0; e2 < 8; ++e2) {
                    int k = EMBED + s * 32 + q * 8 + e2;
                    bfragR[s][nt][e2] = (short)f2bf(W0[(long)k * NG + nt * 256 + u0 + l15]);
                }
        drain_sync();
        if (tid == 0) st32a(flags + F1IX(bid), 1u);

        {   // pre-loop: gx1[0] present (parity-0 helpers, 32 packed flags)
            const unsigned* p0 = (lane < 32) ? flags + FHIX(0, lane) : nullptr;
            if (!wpoll(p0, 1u, 52000.f)) return;
        }
        f32x4 gn[4];                        // prefetch gx1[0]
        #pragma unroll
        for (int nt = 0; nt < 4; ++nt)
            #pragma unroll
            for (int rr = 0; rr < 4; ++rr)
                gn[nt][rr] = ldf32a(ring1 + (size_t)(bbase + q * 4 + rr) * NG + nt * 256 + u0 + l15);

        float c4[4] = {0.f, 0.f, 0.f, 0.f};
        for (int e = 0; e <= 255; ++e) {
            // single combined poll, 3 packed groups:
            //   lanes 0-15 : f1 >= e+1   (h1[e-1] published)
            //   lanes 16-31: f2 >= e-2   (L2 done e-4 -> h1 slot e&3 free), e>=4
            //   lanes 32-63: fh[(e+1)&1] >= e+2 (gx1[e+1] stored), e<=254
            const unsigned* p0 = nullptr; unsigned t0 = 0;
            if (lane < 16)      { p0 = flags + F1IX(lane); t0 = (unsigned)(e + 1); }
            else if (lane < 32) { if (e >= 4) { p0 = flags + F2IX(lane - 16); t0 = (unsigned)(e - 2); } }
            else                { if (e <= 254) { p0 = flags + FHIX((e + 1) & 1, lane - 32); t0 = (unsigned)(e + 2); } }
            if (!wpoll(p0, t0, 51000.f + (float)e)) break;

            short8 a1[8];
            { const unsigned short* hb = h1 + ((e - 1) & 3) * 16384 + arow * 256;
              #pragma unroll
              for (int s = 0; s < 8; ++s) a1[s] = ldh16a(hb + s * 32 + q * 8); }

            f32x4 acc[4] = {gn[0], gn[1], gn[2], gn[3]};
            #pragma unroll
            for (int s = 0; s < 8; ++s)
                #pragma unroll
                for (int nt = 0; nt < 4; ++nt)
                    acc[nt] = MFMA(a1[s], bfragR[s][nt], acc[nt]);

            #pragma unroll
            for (int rr = 0; rr < 4; ++rr) {
                int b = bbase + q * 4 + rr;
                float iv = sigm(acc[0][rr]);
                float jv = tanh_(acc[1][rr]);
                float fv = sigm(acc[2][rr] + 1.0f);
                float ov = sigm(acc[3][rr]);
                float cn = c4[rr] * fv + iv * jv;
                c4[rr] = cn;
                *(unsigned short*)(lds + b * 32 + l15 * 2) = f2bf(tanh_(cn) * ov);
            }
            asm volatile("s_waitcnt lgkmcnt(0)" ::: "memory");
            {   // wave-local repack publish: row bbase+(lane>>2), u64 part lane&3
                int r = bbase + (lane >> 2), p = lane & 3;
                ull v = *(ull*)(lds + r * 32 + p * 8);
                st64a((ull*)(h1 + (e & 3) * 16384 + r * 256 + u0) + p, v);
            }
            drain_sync();
            if (tid == 0) st32a(flags + F1IX(bid), (unsigned)(e + 2));

            if (e <= 254) {                 // prefetch gx1[e+1] (availability already polled)
                const float* g1 = ring1 + (size_t)((e + 1) & 3) * (64 * NG);
                #pragma unroll
                for (int nt = 0; nt < 4; ++nt)
                    #pragma unroll
                    for (int rr = 0; rr < 4; ++rr)
                        gn[nt][rr] = ldf32a(g1 + (size_t)(bbase + q * 4 + rr) * NG + nt * 256 + u0 + l15);
            }
        }

    // =====================================================================
    } else if (bid < NL1 + NL2) {          // ---- L2: x-part (LDS W1x) + rec (reg W1r) ----
        const int idx = bid - NL1, u0 = idx * 16, u = u0 + l15;
        { int r = tid >> 2, p = tid & 3;   // zero h2[-1] (slot 1), own stripe
          st64a((ull*)(h2 + 16384 + r * 256 + u0) + p, 0ULL); }
        float biasx[4];
        short8 bW1r[8][4];
        #pragma unroll
        for (int nt = 0; nt < 4; ++nt) {
            biasx[nt] = b1[nt * 256 + u0 + l15];
            #pragma unroll
            for (int s = 0; s < 8; ++s)
                #pragma unroll
                for (int e2 = 0; e2 < 8; ++e2) {
                    int k = HIDDEN + s * 32 + q * 8 + e2;
                    bW1r[s][nt][e2] = (short)f2bf(W1[(long)k * NG + nt * 256 + u0 + l15]);
                }
        }
        // stage W1x rows 0..255 for this stripe: 8 regions x 4KB (r2-proven)
        for (int i2 = tid; i2 < 8 * 64 * 32; i2 += 256) {
            int k = i2 >> 6, c = i2 & 63;
            int col = (c >> 4) * 256 + u0 + (c & 15);
            int s = k >> 5, kk = k & 31;
            *(unsigned short*)(lds + s * 4096 + swzb(c, c * 64 + kk * 2)) =
                f2bf(W1[(long)k * NG + col]);
        }
        drain_sync();
        if (tid == 0) st32a(flags + F2IX(idx), 1u);

        float c4[4] = {0.f, 0.f, 0.f, 0.f};
        for (int t = 0; t <= 255; ++t) {
            // poll: lanes 0-15: f1 >= t+2 (h1[t] ready); 16-31: f2 >= t+1 (h2[t-1] ready)
            const unsigned* p0 = nullptr; unsigned t0 = 0;
            if (lane < 16)      { p0 = flags + F1IX(lane); t0 = (unsigned)(t + 2); }
            else if (lane < 32) { p0 = flags + F2IX(lane - 16); t0 = (unsigned)(t + 1); }
            if (!wpoll(p0, t0, 54000.f + (float)t)) break;

            short8 a1[8], a2[8];
            const unsigned short* b1p = h1 + (t & 3) * 16384 + arow * 256;
            const unsigned short* b2p = h2 + ((t - 1) & 1) * 16384 + arow * 256;
            #pragma unroll
            for (int s = 0; s < 8; ++s) {
                a1[s] = ldh16a(b1p + s * 32 + q * 8);
                a2[s] = ldh16a(b2p + s * 32 + q * 8);
            }

            f32x4 acc[4];
            #pragma unroll
            for (int nt = 0; nt < 4; ++nt)
                acc[nt] = (f32x4){biasx[nt], biasx[nt], biasx[nt], biasx[nt]};
            #pragma unroll
            for (int s = 0; s < 8; ++s)
                #pragma unroll
                for (int nt = 0; nt < 4; ++nt) {
                    int c = nt * 16 + l15;
                    short8 bx = *(const short8*)(lds + s * 4096 + swzb(c, c * 64 + q * 16));
                    acc[nt] = MFMA(a1[s], bx, acc[nt]);
                }
            #pragma unroll
            for (int s = 0; s < 8; ++s)
                #pragma unroll
                for (int nt = 0; nt < 4; ++nt)
                    acc[nt] = MFMA(a2[s], bW1r[s][nt], acc[nt]);

            #pragma unroll
            for (int rr = 0; rr < 4; ++rr) {
                int b = bbase + q * 4 + rr;
                float iv = sigm(acc[0][rr]);
                float jv = tanh_(acc[1][rr]);
                float fv = sigm(acc[2][rr] + 1.0f);
                float ov = sigm(acc[3][rr]);
                float cn = c4[rr] * fv + iv * jv;
                c4[rr] = cn;
                float hn = tanh_(cn) * ov;
                if (t == 255) out[b * HIDDEN + u] = hn;
                else *(unsigned short*)(lds + 32768 + b * 32 + l15 * 2) = f2bf(hn);
            }
            if (t == 255) break;
            asm volatile("s_waitcnt lgkmcnt(0)" ::: "memory");
            {   // wave-local repack publish
                int r = bbase + (lane >> 2), p = lane & 3;
                ull v = *(ull*)(lds + 32768 + r * 32 + p * 8);
                st64a((ull*)(h2 + (t & 1) * 16384 + r * 256 + u0) + p, v);
            }
            drain_sync();
            if (tid == 0) st32a(flags + F2IX(idx), (unsigned)(t + 2));
        }

    // =====================================================================
    } else {                               // ---- gx1 helpers (parity x 32 slices) ----
        const int hidx = bid - NL1 - NL2;  // 0..63
        const int par = hidx & 1, slice = hidx >> 1, hc0 = slice * 32;
        float biasH[2];
        #pragma unroll
        for (int gi = 0; gi < 2; ++gi) biasH[gi] = b0[hc0 + gi * 16 + l15];
        for (int i2 = tid; i2 < 20 * 32 * 32; i2 += 256) {   // W0 x-part hi+lo residual
            int k = i2 >> 5, c = i2 & 31;
            int s = k >> 5, kk = k & 31;
            int row = (s >= 10) ? (k - 320) : k;
            float v = W0[(long)row * NG + hc0 + c];
            unsigned short hv = f2bf(v);
            if (s >= 10) hv = f2bf(v - bf2f(hv));
            *(unsigned short*)(lds + s * 2048 + swzb(c, c * 64 + kk * 2)) = hv;
        }
        __syncthreads();

        for (int t = par; t <= 255; t += 2) {
            int xid = xin[arow * SEQ + t];
            const float* erow = emb + (long)xid * EMBED;
            short8 ac[10];
            #pragma unroll
            for (int s = 0; s < 10; ++s) {
                int kb = s * 32 + q * 8;
                #pragma unroll
                for (int hh = 0; hh < 2; ++hh) {
                    int k4 = kb + hh * 4;
                    if (k4 < EMBED) {
                        f32x4 v = *(const f32x4*)(erow + k4);
                        #pragma unroll
                        for (int e2 = 0; e2 < 4; ++e2) ac[s][hh * 4 + e2] = (short)f2bf(v[e2]);
                    } else {
                        #pragma unroll
                        for (int e2 = 0; e2 < 4; ++e2) ac[s][hh * 4 + e2] = 0;
                    }
                }
            }
            f32x4 accg[2];
            #pragma unroll
            for (int gi = 0; gi < 2; ++gi)
                accg[gi] = (f32x4){biasH[gi], biasH[gi], biasH[gi], biasH[gi]};
            #pragma unroll
            for (int s = 0; s < 20; ++s) {
                short8 a = ac[(s < 10) ? s : s - 10];
                #pragma unroll
                for (int gi = 0; gi < 2; ++gi) {
                    int c = gi * 16 + l15;
                    short8 b = *(const short8*)(lds + s * 2048 + swzb(c, c * 64 + q * 16));
                    accg[gi] = MFMA(a, b, accg[gi]);
                }
            }
            // slot gate: all L1 f1 >= t-2 (their gx1[t-4] prefetch loads drained)
            if (t >= 4) {
                const unsigned* p0 = (lane < 16) ? flags + F1IX(lane) : nullptr;
                if (!wpoll(p0, (unsigned)(t - 2), 55000.f + (float)t)) break;
            }
            float* dst = ring1 + (size_t)(t & 3) * (64 * NG);
            #pragma unroll
            for (int gi = 0; gi < 2; ++gi)
                #pragma unroll
                for (int rr = 0; rr < 4; ++rr)
                    stf32a(dst + (size_t)(bbase + q * 4 + rr) * NG + hc0 + gi * 16 + l15, accg[gi][rr]);
            drain_sync();
            if (tid == 0) st32a(flags + FHIX(par, slice), (unsigned)(t + 1));
        }
    }
}

__global__ void ws_too_small_sentinel(float* out, int n) {
    int i = blockIdx.x * 256 + threadIdx.x;
    if (i < n) out[i] = 31337.0f;
}

extern "C" void kernel_launch(void* const* d_in, const int* in_sizes, int n_in,
                              void* d_out, int out_size, void* d_ws, size_t ws_size,
                              hipStream_t stream)
{
    const int*   xin = (const int*)d_in[0];
    const float* emb = (const float*)d_in[1];
    const float* W0  = (const float*)d_in[2];
    const float* b0  = (const float*)d_in[3];
    const float* W1  = (const float*)d_in[4];
    const float* b1  = (const float*)d_in[5];
    float* out = (float*)d_out;

    const size_t OFF_FLAGS = 0;                           // 4 KB (96 packed flags)
    const size_t OFF_H1    = 4096;                        // 128 KB (depth 4)
    const size_t OFF_H2    = OFF_H1 + 131072;             // 64 KB (depth 2)
    const size_t OFF_RING1 = OFF_H2 + 65536;              // 1 MB (depth 4)
    const size_t NEED      = OFF_RING1 + (size_t)4 * 64 * NG * 4;   // 1,249,280 B (< proven 1,589,248)

    if (ws_size < NEED) {   // diagnostic: absmax ~31337 => ws too small
        ws_too_small_sentinel<<<(out_size + 255) / 256, 256, 0, stream>>>(out, out_size);
        return;
    }

    char* ws = (char*)d_ws;
    unsigned*       flags = (unsigned*)(ws + OFF_FLAGS);
    unsigned short* h1    = (unsigned short*)(ws + OFF_H1);
    unsigned short* h2    = (unsigned short*)(ws + OFF_H2);
    float*          ring1 = (float*)(ws + OFF_RING1);

    hipMemsetAsync(flags, 0, 4096, stream);
    lstm_v8<<<dim3(NBLK), dim3(256), 41088, stream>>>(
        xin, emb, W0, b0, W1, b1, flags, h1, h2, ring1, out);
}